// Round 1
// baseline (904.155 us; speedup 1.0000x reference)
//
#include <hip/hip_runtime.h>
#include <cstdint>
#include <cstddef>

#define D 2048
#define L 8
#define BM 128
#define BK 64

typedef _Float16 f16;
typedef _Float16 f16x2 __attribute__((ext_vector_type(2)));
typedef _Float16 f16x4 __attribute__((ext_vector_type(4)));
typedef _Float16 f16x8 __attribute__((ext_vector_type(8)));
typedef float f32x4 __attribute__((ext_vector_type(4)));

// ---------------- init: split A into pos/neg fp16 into both chains ----------
__global__ __launch_bounds__(256) void k_init_state(
    const float* __restrict__ A,
    f16* __restrict__ AlP, f16* __restrict__ AlN,
    f16* __restrict__ AuP, f16* __restrict__ AuN) {
  size_t i = ((size_t)blockIdx.x * 256 + threadIdx.x) * 8;
  f32x4 a0 = *(const f32x4*)(A + i);
  f32x4 a1 = *(const f32x4*)(A + i + 4);
  f16x8 p, n;
#pragma unroll
  for (int j = 0; j < 4; ++j) {
    p[j]     = (f16)fmaxf(a0[j], 0.f);  n[j]     = (f16)fminf(a0[j], 0.f);
    p[j + 4] = (f16)fmaxf(a1[j], 0.f);  n[j + 4] = (f16)fminf(a1[j], 0.f);
  }
  *(f16x8*)(AlP + i) = p; *(f16x8*)(AlN + i) = n;
  *(f16x8*)(AuP + i) = p; *(f16x8*)(AuN + i) = n;
}

__global__ void k_init_bias(const float* __restrict__ b,
                            float* __restrict__ bl, float* __restrict__ bu) {
  int i = blockIdx.x * 256 + threadIdx.x;
  float v = b[i];
  bl[i] = v; bu[i] = v;
}

// ---------------- transpose + convert: dst[n][k] = (f16)src[k][n] ------------
__global__ __launch_bounds__(256) void k_transpose(
    const float* __restrict__ srcAl, const float* __restrict__ srcAu,
    f16* __restrict__ dstL, f16* __restrict__ dstU) {
  __shared__ float t[64][65];
  const float* src = blockIdx.z ? srcAu : srcAl;
  f16* dst = blockIdx.z ? dstU : dstL;
  int nb = blockIdx.x * 64;   // src col base (output row)
  int kb = blockIdx.y * 64;   // src row base (output col)
  int tid = threadIdx.x;
  int c = tid & 63, r0 = tid >> 6;
#pragma unroll
  for (int i = 0; i < 64; i += 4)
    t[r0 + i][c] = src[(size_t)(kb + r0 + i) * D + nb + c];
  __syncthreads();
  int cc = (tid & 31) * 2, rr0 = tid >> 5;
#pragma unroll
  for (int i = 0; i < 64; i += 8) {
    int rr = rr0 + i;
    f16x2 h;
    h[0] = (f16)t[cc][rr];
    h[1] = (f16)t[cc + 1][rr];
    *(f16x2*)(dst + (size_t)(nb + rr) * D + kb + cc) = h;
  }
}

// ---------------- async global->LDS helper ----------------------------------
__device__ __forceinline__ void gload16(const void* g, void* l) {
  __builtin_amdgcn_global_load_lds(
      (const __attribute__((address_space(1))) void*)g,
      (__attribute__((address_space(3))) void*)l, 16, 0, 0);
}

// ---------------- the step GEMM ---------------------------------------------
// z=0: newAl = AlP@BlT' + AlN@BuT'   (BlT[n][k] = dAl[k][n])
// z=1: newAu = AuP@BuT' + AuN@BlT'
// Epilogue splits accumulator into pos/neg fp16 state for next step.
__global__ __launch_bounds__(256) void k_step_gemm(
    const f16* __restrict__ AlP, const f16* __restrict__ AlN,
    const f16* __restrict__ AuP, const f16* __restrict__ AuN,
    const f16* __restrict__ BlT, const f16* __restrict__ BuT,
    f16* __restrict__ oAlP, f16* __restrict__ oAlN,
    f16* __restrict__ oAuP, f16* __restrict__ oAuN) {
  __shared__ __align__(16) f16 lA[BM][BK];
  __shared__ __align__(16) f16 lB[BM][BK];
  const int z = blockIdx.z;
  const f16* Ap = z ? AuP : AlP;
  const f16* An = z ? AuN : AlN;
  const f16* B1 = z ? BuT : BlT;
  const f16* B2 = z ? BlT : BuT;
  f16* oP = z ? oAuP : oAlP;
  f16* oN = z ? oAuN : oAlN;

  const int m0 = blockIdx.x * BM;   // output row base
  const int n0 = blockIdx.y * BM;   // output col base
  const int tid = threadIdx.x;
  const int wave = tid >> 6, lane = tid & 63;
  const int wm = (wave >> 1) * 64, wn = (wave & 1) * 64;

  f32x4 acc[4][4];  // acc[n][m]; lane holds C[m_abs][n_abs + r]
#pragma unroll
  for (int i = 0; i < 4; ++i)
#pragma unroll
    for (int j = 0; j < 4; ++j)
      acc[i][j] = (f32x4){0.f, 0.f, 0.f, 0.f};

  const int lrow = lane >> 3;         // row within 8-row chunk
  const int lcol = (lane & 7) * 8;    // f16 offset within row (16B per lane)

  for (int phase = 0; phase < 2; ++phase) {
    const f16* Aop = phase ? An : Ap;
    const f16* Bop = phase ? B2 : B1;
    for (int kt = 0; kt < D / BK; ++kt) {
      const int k0 = kt * BK;
#pragma unroll
      for (int i = 0; i < 4; ++i) {
        const int chunk = wave * 4 + i;           // 16 chunks of 8 rows
        const int row = chunk * 8 + lrow;
        gload16(Aop + (size_t)(m0 + row) * D + k0 + lcol, &lA[chunk * 8][0]);
        gload16(Bop + (size_t)(n0 + row) * D + k0 + lcol, &lB[chunk * 8][0]);
      }
      __syncthreads();
#pragma unroll
      for (int h = 0; h < 2; ++h) {
        const int kk = h * 32 + (lane >> 4) * 8;
        f16x8 af[4], bf[4];
#pragma unroll
        for (int m = 0; m < 4; ++m)
          af[m] = *(const f16x8*)&lA[wm + m * 16 + (lane & 15)][kk];
#pragma unroll
        for (int n = 0; n < 4; ++n)
          bf[n] = *(const f16x8*)&lB[wn + n * 16 + (lane & 15)][kk];
#pragma unroll
        for (int n = 0; n < 4; ++n)
#pragma unroll
          for (int m = 0; m < 4; ++m)
            // swapped roles: X = B^T fragment (rows=n), Y = A fragment (cols=m)
            acc[n][m] = __builtin_amdgcn_mfma_f32_16x16x32_f16(
                bf[n], af[m], acc[n][m], 0, 0, 0);
      }
      __syncthreads();
    }
  }

  // epilogue: lane holds C[row][col..col+3]; split pos/neg, store fp16x4
#pragma unroll
  for (int n = 0; n < 4; ++n) {
#pragma unroll
    for (int m = 0; m < 4; ++m) {
      const int row = m0 + wm + m * 16 + (lane & 15);
      const int col = n0 + wn + n * 16 + (lane >> 4) * 4;
      f16x4 p, q;
#pragma unroll
      for (int r = 0; r < 4; ++r) {
        float v = acc[n][m][r];
        p[r] = (f16)fmaxf(v, 0.f);
        q[r] = (f16)fminf(v, 0.f);
      }
      *(f16x4*)(oP + (size_t)row * D + col) = p;
      *(f16x4*)(oN + (size_t)row * D + col) = q;
    }
  }
}

// ---------------- bias matvec: b += P@v1 + N@v2 (in place, old state) --------
__global__ __launch_bounds__(256) void k_bias(
    const f16* __restrict__ AlP, const f16* __restrict__ AlN,
    const f16* __restrict__ AuP, const f16* __restrict__ AuN,
    const float* __restrict__ dbl, const float* __restrict__ dbu,
    float* __restrict__ bl, float* __restrict__ bu) {
  const int wave = threadIdx.x >> 6, lane = threadIdx.x & 63;
  const int row = blockIdx.x * 4 + wave;
  const f16 *P, *N; const float *v1, *v2; float* bb;
  if (blockIdx.y == 0) { P = AlP; N = AlN; v1 = dbl; v2 = dbu; bb = bl; }
  else                 { P = AuP; N = AuN; v1 = dbu; v2 = dbl; bb = bu; }
  const f16* pr = P + (size_t)row * D;
  const f16* nr = N + (size_t)row * D;
  float acc = 0.f;
  for (int k = lane * 8; k < D; k += 64 * 8) {
    f16x8 pv = *(const f16x8*)(pr + k);
    f16x8 nv = *(const f16x8*)(nr + k);
#pragma unroll
    for (int j = 0; j < 8; ++j)
      acc += (float)pv[j] * v1[k + j] + (float)nv[j] * v2[k + j];
  }
#pragma unroll
  for (int off = 32; off > 0; off >>= 1) acc += __shfl_down(acc, off);
  if (lane == 0) bb[row] += acc;
}

// ---------------- final bounds ----------------------------------------------
__global__ __launch_bounds__(256) void k_final(
    const f16* __restrict__ AlP, const f16* __restrict__ AlN,
    const f16* __restrict__ AuP, const f16* __restrict__ AuN,
    const float* __restrict__ lo, const float* __restrict__ up,
    const float* __restrict__ bl, const float* __restrict__ bu,
    float* __restrict__ out) {
  const int wave = threadIdx.x >> 6, lane = threadIdx.x & 63;
  const int row = blockIdx.x * 4 + wave;
  const f16 *P, *N; const float *v1, *v2; const float* bb; int obase;
  if (blockIdx.y == 0) { P = AlP; N = AlN; v1 = lo; v2 = up; bb = bl; obase = 0; }
  else                 { P = AuP; N = AuN; v1 = up; v2 = lo; bb = bu; obase = D; }
  const f16* pr = P + (size_t)row * D;
  const f16* nr = N + (size_t)row * D;
  float acc = 0.f;
  for (int k = lane * 8; k < D; k += 64 * 8) {
    f16x8 pv = *(const f16x8*)(pr + k);
    f16x8 nv = *(const f16x8*)(nr + k);
#pragma unroll
    for (int j = 0; j < 8; ++j)
      acc += (float)pv[j] * v1[k + j] + (float)nv[j] * v2[k + j];
  }
#pragma unroll
  for (int off = 32; off > 0; off >>= 1) acc += __shfl_down(acc, off);
  if (lane == 0) out[obase + row] = acc + bb[row];
}

// ---------------- host ------------------------------------------------------
extern "C" void kernel_launch(void* const* d_in, const int* in_sizes, int n_in,
                              void* d_out, int out_size, void* d_ws, size_t ws_size,
                              hipStream_t stream) {
  (void)in_sizes; (void)n_in; (void)out_size; (void)ws_size;
  const float* A   = (const float*)d_in[0];
  const float* b   = (const float*)d_in[1];
  const float* hAl = (const float*)d_in[2];
  const float* hAu = (const float*)d_in[3];
  const float* hbl = (const float*)d_in[4];
  const float* hbu = (const float*)d_in[5];
  const float* lo  = (const float*)d_in[6];
  const float* up  = (const float*)d_in[7];
  float* out = (float*)d_out;

  const size_t MS = (size_t)D * D;
  f16* st  = (f16*)d_ws;            // 2 ping-pong sets x {AlP,AlN,AuP,AuN}
  f16* BlT = st + 8 * MS;
  f16* BuT = BlT + MS;
  float* bl = (float*)(BuT + MS);
  float* bu = bl + D;

  auto S = [&](int set, int idx) { return st + ((size_t)set * 4 + idx) * MS; };

  k_init_state<<<dim3((unsigned)(MS / (256 * 8))), 256, 0, stream>>>(
      A, S(0, 0), S(0, 1), S(0, 2), S(0, 3));
  k_init_bias<<<dim3(D / 256), 256, 0, stream>>>(b, bl, bu);

  int cur = 0;
  for (int t = 0; t < L; ++t) {
    const int layer = L - 1 - t;
    k_transpose<<<dim3(D / 64, D / 64, 2), 256, 0, stream>>>(
        hAl + (size_t)layer * MS, hAu + (size_t)layer * MS, BlT, BuT);
    k_bias<<<dim3(D / 4, 2), 256, 0, stream>>>(
        S(cur, 0), S(cur, 1), S(cur, 2), S(cur, 3),
        hbl + (size_t)layer * D, hbu + (size_t)layer * D, bl, bu);
    const int nxt = cur ^ 1;
    k_step_gemm<<<dim3(D / BM, D / BM, 2), 256, 0, stream>>>(
        S(cur, 0), S(cur, 1), S(cur, 2), S(cur, 3), BlT, BuT,
        S(nxt, 0), S(nxt, 1), S(nxt, 2), S(nxt, 3));
    cur = nxt;
  }
  k_final<<<dim3(D / 4, 2), 256, 0, stream>>>(
      S(cur, 0), S(cur, 1), S(cur, 2), S(cur, 3), lo, up, bl, bu, out);
}

// Round 2
// 755.643 us; speedup vs baseline: 1.1965x; 1.1965x over previous
//
#include <hip/hip_runtime.h>
#include <cstdint>
#include <cstddef>

#define D 2048
#define L 8
#define KT 4096            // stacked K (pos|neg)
#define BM 256
#define BN 128
#define BK 64
#define NT (KT / BK)       // 64 K-tiles
#define BUFSZ ((BM + BN) * BK)   // f16 elems per LDS buffer

typedef _Float16 f16;
typedef _Float16 f16x2 __attribute__((ext_vector_type(2)));
typedef _Float16 f16x4 __attribute__((ext_vector_type(4)));
typedef _Float16 f16x8 __attribute__((ext_vector_type(8)));
typedef float f32x4 __attribute__((ext_vector_type(4)));

__device__ __forceinline__ void gload16(const void* g, void* l) {
  __builtin_amdgcn_global_load_lds(
      (const __attribute__((address_space(1))) void*)g,
      (__attribute__((address_space(3))) void*)l, 16, 0, 0);
}

// ---- init: A -> Abig = [[A+ | A-] ; [A- | A+]] in f16 ----------------------
__global__ __launch_bounds__(256) void k_init_state(
    const float* __restrict__ A, f16* __restrict__ Ab) {
  size_t i = ((size_t)blockIdx.x * 256 + threadIdx.x) * 8;
  int m = (int)(i >> 11);
  int k = (int)(i & 2047);
  f32x4 a0 = *(const f32x4*)(A + i);
  f32x4 a1 = *(const f32x4*)(A + i + 4);
  f16x8 p, n;
#pragma unroll
  for (int j = 0; j < 4; ++j) {
    p[j]     = (f16)fmaxf(a0[j], 0.f);  n[j]     = (f16)fminf(a0[j], 0.f);
    p[j + 4] = (f16)fmaxf(a1[j], 0.f);  n[j + 4] = (f16)fminf(a1[j], 0.f);
  }
  size_t lo = (size_t)m * KT + k;
  size_t hi = (size_t)(D + m) * KT + k;
  *(f16x8*)(Ab + lo) = p;      *(f16x8*)(Ab + lo + D) = n;
  *(f16x8*)(Ab + hi) = n;      *(f16x8*)(Ab + hi + D) = p;
}

__global__ void k_init_bias(const float* __restrict__ b,
                            float* __restrict__ bl, float* __restrict__ bu) {
  int i = blockIdx.x * 256 + threadIdx.x;
  float v = b[i];
  bl[i] = v; bu[i] = v;
}

// ---- transpose+convert: Bbig[n][koff+k] = (f16)src[k][n] -------------------
__global__ __launch_bounds__(256) void k_transpose(
    const float* __restrict__ srcAl, const float* __restrict__ srcAu,
    f16* __restrict__ Bb) {
  __shared__ float t[64][65];
  const float* src = blockIdx.z ? srcAu : srcAl;
  const int koff = blockIdx.z ? D : 0;
  int nb = blockIdx.x * 64;
  int kb = blockIdx.y * 64;
  int tid = threadIdx.x;
  int c = tid & 63, r0 = tid >> 6;
#pragma unroll
  for (int i = 0; i < 64; i += 4)
    t[r0 + i][c] = src[(size_t)(kb + r0 + i) * D + nb + c];
  __syncthreads();
  int cc = (tid & 31) * 2, rr0 = tid >> 5;
#pragma unroll
  for (int i = 0; i < 64; i += 8) {
    int rr = rr0 + i;
    f16x2 h;
    h[0] = (f16)t[cc][rr];
    h[1] = (f16)t[cc + 1][rr];
    *(f16x2*)(Bb + (size_t)(nb + rr) * KT + koff + kb + cc) = h;
  }
}

// ---- the step GEMM: C[4096][2048] = Abig @ BbigT^T, sign-split epilogue ----
__global__ __launch_bounds__(512, 2) void k_gemm(
    const f16* __restrict__ A,    // [2D][KT]
    const f16* __restrict__ BT,   // [D][KT]
    f16* __restrict__ An) {       // [2D][KT] next state
  __shared__ __align__(16) f16 lds[3 * BUFSZ];   // 144 KiB tri-buffer
  const int m0 = blockIdx.y * BM;
  const int n0 = blockIdx.x * BN;
  const int tid = threadIdx.x;
  const int wave = tid >> 6, lane = tid & 63;
  const int wm = (wave & 3) * 64, wn = (wave >> 2) * 64;
  const int sub = lane >> 3;                  // row within 8-row region
  const int cg = ((lane & 7) ^ sub) * 8;      // inverse-swizzled src chunk
  const int lr = lane & 15, lq = lane >> 4;

  f32x4 acc[4][4];
#pragma unroll
  for (int m = 0; m < 4; ++m)
#pragma unroll
    for (int n = 0; n < 4; ++n)
      acc[m][n] = (f32x4){0.f, 0.f, 0.f, 0.f};

  auto stage = [&](int kt, int buf) {
    f16* bA = lds + buf * BUFSZ;
    f16* bB = bA + BM * BK;
    const size_t gk = (size_t)kt * BK;
#pragma unroll
    for (int i = 0; i < 4; ++i) {
      const int r = i * 8 + wave;             // 32 regions x 8 rows (A)
      gload16(A + (size_t)(m0 + r * 8 + sub) * KT + gk + cg, bA + r * 512);
    }
#pragma unroll
    for (int i = 0; i < 2; ++i) {
      const int r = i * 8 + wave;             // 16 regions x 8 rows (B)
      gload16(BT + (size_t)(n0 + r * 8 + sub) * KT + gk + cg, bB + r * 512);
    }
  };

  // prologue: 2 tiles in flight, wait for the first
  stage(0, 0);
  stage(1, 1);
  asm volatile("s_waitcnt vmcnt(6)" ::: "memory");
  __builtin_amdgcn_sched_barrier(0);
  __builtin_amdgcn_s_barrier();
  __builtin_amdgcn_sched_barrier(0);

  for (int t = 0; t < NT; ++t) {
    const f16* bA = lds + (t % 3) * BUFSZ;
    const f16* bB = bA + BM * BK;
    if (t + 2 < NT) stage(t + 2, (t + 2) % 3);   // prefetch 2 tiles ahead
#pragma unroll
    for (int s = 0; s < 2; ++s) {
      const int ch = ((s * 4 + lq) ^ (lane & 7)) * 8;  // swizzled read chunk
      f16x8 af[4], bf[4];
#pragma unroll
      for (int m = 0; m < 4; ++m)
        af[m] = *(const f16x8*)(bA + (wm + m * 16 + lr) * BK + ch);
#pragma unroll
      for (int n = 0; n < 4; ++n)
        bf[n] = *(const f16x8*)(bB + (wn + n * 16 + lr) * BK + ch);
      __builtin_amdgcn_s_setprio(1);
#pragma unroll
      for (int m = 0; m < 4; ++m)
#pragma unroll
        for (int n = 0; n < 4; ++n)
          acc[m][n] = __builtin_amdgcn_mfma_f32_16x16x32_f16(
              bf[n], af[m], acc[m][n], 0, 0, 0);
      __builtin_amdgcn_s_setprio(0);
    }
    // counted wait: keep next tile's 6 loads in flight across the barrier
    if (t + 2 < NT) {
      asm volatile("s_waitcnt vmcnt(6)" ::: "memory");
    } else if (t + 1 < NT) {
      asm volatile("s_waitcnt vmcnt(0)" ::: "memory");
    }
    __builtin_amdgcn_sched_barrier(0);
    __builtin_amdgcn_s_barrier();
    __builtin_amdgcn_sched_barrier(0);
  }

  const int low = (m0 < D) ? 1 : 0;   // block-uniform: lower vs upper chain
#pragma unroll
  for (int m = 0; m < 4; ++m) {
#pragma unroll
    for (int n = 0; n < 4; ++n) {
      const size_t row = (size_t)(m0 + wm + m * 16 + lr);
      const int col = n0 + wn + n * 16 + lq * 4;
      f16x4 p, q;
#pragma unroll
      for (int r = 0; r < 4; ++r) {
        float v = acc[m][n][r];
        p[r] = (f16)fmaxf(v, 0.f);
        q[r] = (f16)fminf(v, 0.f);
      }
      f16* base = An + row * KT + col;
      if (low) { *(f16x4*)base = p; *(f16x4*)(base + D) = q; }
      else     { *(f16x4*)base = q; *(f16x4*)(base + D) = p; }
    }
  }
}

// ---- bias: bb[R] += sum_k Ab[R][k]*dbl[k] + Ab[R][k+D]*dbu[k] --------------
__global__ __launch_bounds__(256) void k_bias(
    const f16* __restrict__ Ab, const float* __restrict__ dbl,
    const float* __restrict__ dbu, float* __restrict__ bl,
    float* __restrict__ bu) {
  const int wave = threadIdx.x >> 6, lane = threadIdx.x & 63;
  const int R = blockIdx.x * 4 + wave;    // 0..4095
  const f16* row = Ab + (size_t)R * KT;
  float acc = 0.f;
  for (int k = lane * 8; k < D; k += 512) {
    f16x8 a = *(const f16x8*)(row + k);
    f16x8 c = *(const f16x8*)(row + D + k);
#pragma unroll
    for (int j = 0; j < 8; ++j)
      acc += (float)a[j] * dbl[k + j] + (float)c[j] * dbu[k + j];
  }
#pragma unroll
  for (int off = 32; off > 0; off >>= 1) acc += __shfl_down(acc, off);
  if (lane == 0) {
    if (R < D) bl[R] += acc; else bu[R - D] += acc;
  }
}

// ---- final: out[R] = sum_k Ab[R][k]*lo[k] + Ab[R][k+D]*up[k] + bias --------
__global__ __launch_bounds__(256) void k_final(
    const f16* __restrict__ Ab, const float* __restrict__ lo,
    const float* __restrict__ up, const float* __restrict__ bl,
    const float* __restrict__ bu, float* __restrict__ out) {
  const int wave = threadIdx.x >> 6, lane = threadIdx.x & 63;
  const int R = blockIdx.x * 4 + wave;    // 0..4095
  const f16* row = Ab + (size_t)R * KT;
  float acc = 0.f;
  for (int k = lane * 8; k < D; k += 512) {
    f16x8 a = *(const f16x8*)(row + k);
    f16x8 c = *(const f16x8*)(row + D + k);
#pragma unroll
    for (int j = 0; j < 8; ++j)
      acc += (float)a[j] * lo[k + j] + (float)c[j] * up[k + j];
  }
#pragma unroll
  for (int off = 32; off > 0; off >>= 1) acc += __shfl_down(acc, off);
  if (lane == 0)
    out[R] = acc + (R < D ? bl[R] : bu[R - D]);
}

// ---- host ------------------------------------------------------------------
extern "C" void kernel_launch(void* const* d_in, const int* in_sizes, int n_in,
                              void* d_out, int out_size, void* d_ws, size_t ws_size,
                              hipStream_t stream) {
  (void)in_sizes; (void)n_in; (void)out_size; (void)ws_size;
  const float* A   = (const float*)d_in[0];
  const float* b   = (const float*)d_in[1];
  const float* hAl = (const float*)d_in[2];
  const float* hAu = (const float*)d_in[3];
  const float* hbl = (const float*)d_in[4];
  const float* hbu = (const float*)d_in[5];
  const float* lo  = (const float*)d_in[6];
  const float* up  = (const float*)d_in[7];
  float* out = (float*)d_out;

  const size_t AS = (size_t)2 * D * KT;     // Abig elems (f16)
  const size_t MS = (size_t)D * D;
  f16* Ab0 = (f16*)d_ws;
  f16* Ab1 = Ab0 + AS;
  f16* Bb  = Ab1 + AS;                      // [D][KT]
  float* bl = (float*)(Bb + (size_t)D * KT);
  float* bu = bl + D;

  k_init_state<<<dim3((unsigned)(MS / (256 * 8))), 256, 0, stream>>>(A, Ab0);
  k_init_bias<<<dim3(D / 256), 256, 0, stream>>>(b, bl, bu);

  f16* cur = Ab0;
  f16* nxt = Ab1;
  for (int t = 0; t < L; ++t) {
    const int layer = L - 1 - t;
    k_transpose<<<dim3(D / 64, D / 64, 2), 256, 0, stream>>>(
        hAl + (size_t)layer * MS, hAu + (size_t)layer * MS, Bb);
    k_bias<<<dim3(2 * D / 4), 256, 0, stream>>>(
        cur, hbl + (size_t)layer * D, hbu + (size_t)layer * D, bl, bu);
    k_gemm<<<dim3(D / BN, 2 * D / BM), 512, 0, stream>>>(cur, Bb, nxt);
    f16* tmp = cur; cur = nxt; nxt = tmp;
  }
  k_final<<<dim3(2 * D / 4), 256, 0, stream>>>(cur, lo, up, bl, bu, out);
}